// Round 5
// baseline (562.608 us; speedup 1.0000x reference)
//
#include <hip/hip_runtime.h>
#include <hip/hip_bf16.h>

// Problem: N=32, T=2048, H=1024, D=384
//   h_proj = gru(N,T,H) @ W_h(H,H); energy = tanh(h_proj + c_proj + bias)
//   scores = energy . v ; weights = softmax_T(scores); context = sum_t w*gru
#define N_B 32
#define T_S 2048
#define H_D 1024
#define D_C 384
#define NT  (N_B * T_S)   // 65536

typedef __attribute__((ext_vector_type(8))) short bf16x8;
typedef __attribute__((ext_vector_type(4))) float f32x4;

__device__ __forceinline__ ushort f2bf(float f) {
    union { float f; unsigned u; } x; x.f = f;
    unsigned u = x.u;
    unsigned r = (u + 0x7FFFu + ((u >> 16) & 1u)) >> 16;  // RNE
    return (ushort)r;
}

// packed fp32x2 -> bf16x2 (v_cvt_pk_bf16_f32 on gfx950)
__device__ __forceinline__ unsigned pkbf(float a, float b) {
    __hip_bfloat162 h = __float22bfloat162_rn(make_float2(a, b));
    union { __hip_bfloat162 h; unsigned u; } c; c.h = h;
    return c.u;
}

__device__ __forceinline__ float fast_tanh(float x) {
    float e = __expf(2.0f * x);
    return 1.0f - 2.0f / (e + 1.0f);
}

// async global->LDS, 16B per lane; LDS dest = wave-uniform base + lane*16
__device__ __forceinline__ void gl2lds16(const void* g, void* l) {
    __builtin_amdgcn_global_load_lds(
        (const __attribute__((address_space(1))) void*)g,
        (__attribute__((address_space(3))) void*)l, 16, 0, 0);
}

// ---------------- W_h (H,H) fp32 -> Wt (H,H) bf16 transposed: Wt[k][h] = W_h[h][k]
__global__ __launch_bounds__(256) void transpose_kernel(
    const float* __restrict__ W, ushort* __restrict__ Wt)
{
    __shared__ ushort tile[64 * 66];
    const int bx = blockIdx.x & 15;
    const int by = blockIdx.x >> 4;
    const int t = threadIdx.x;
    #pragma unroll
    for (int i = 0; i < 16; ++i) {
        int idx = t + i * 256;
        int r = idx >> 6, c = idx & 63;
        tile[r * 66 + c] = f2bf(W[(size_t)(by * 64 + r) * H_D + bx * 64 + c]);
    }
    __syncthreads();
    #pragma unroll
    for (int i = 0; i < 16; ++i) {
        int idx = t + i * 256;
        int r = idx >> 6, c = idx & 63;
        Wt[(size_t)(bx * 64 + r) * H_D + by * 64 + c] = tile[c * 66 + r];
    }
}

// ---------------- c_proj[n,k] += sum_{d in slice} cond[n,d]*W_c[d,k] (+bias)
__global__ __launch_bounds__(256) void cproj_kernel(
    const float* __restrict__ cond, const float* __restrict__ Wc,
    const float* __restrict__ bias, float* __restrict__ cproj)
{
    const int idx = blockIdx.x * 256 + threadIdx.x;  // 32768
    const int n = idx >> 10, k = idx & 1023;
    const int d0 = blockIdx.y * 96;
    float a0 = (blockIdx.y == 0) ? bias[k] : 0.f;
    float a1 = 0.f, a2 = 0.f, a3 = 0.f;
    const float* cp = cond + n * D_C;
    for (int d = d0; d < d0 + 96; d += 4) {
        a0 = fmaf(cp[d + 0], Wc[(size_t)(d + 0) * H_D + k], a0);
        a1 = fmaf(cp[d + 1], Wc[(size_t)(d + 1) * H_D + k], a1);
        a2 = fmaf(cp[d + 2], Wc[(size_t)(d + 2) * H_D + k], a2);
        a3 = fmaf(cp[d + 3], Wc[(size_t)(d + 3) * H_D + k], a3);
    }
    atomicAdd(&cproj[idx], (a0 + a1) + (a2 + a3));
}

// ---------------- GEMM + tanh + dot-v -> per-kb partial scores
// A read as fp32 directly from gru, converted in-register (v_cvt_pk_bf16_f32)
// and staged to LDS with XOR k-chunk swizzle; B (bf16 Wt) via global_load_lds.
// 1D grid 4096, XCD swizzle (id%8 = mb%8): 8 kb-blocks of one mb share one
// XCD's L2, so the fp32 A tile is fetched from HBM once.
__global__ __launch_bounds__(256) void gemm4_kernel(
    const float* __restrict__ gru, const ushort* __restrict__ Wt,
    const float* __restrict__ cproj, const float* __restrict__ v,
    float* __restrict__ spart)
{
    __shared__ __align__(16) ushort As[128 * 64];   // 16 KiB
    __shared__ __align__(16) ushort Bs[128 * 64];   // 16 KiB
    __shared__ float red[2][2][4][16];
    const int id = blockIdx.x;
    const int mb = (id & 7) + ((id >> 6) << 3);   // XCD = id%8 = mb%8
    const int kb = (id >> 3) & 7;
    const int m0 = mb * 128;
    const int nbatch = mb >> 4;
    const int t = threadIdx.x;
    const int lane = t & 63, wave = t >> 6;
    const int wm = wave & 1, wn = wave >> 1;
    const int q = lane >> 4, ln = lane & 15;
    const int x7 = ln & 7;

    // A fp32 staging map: thread t -> row (t>>4)+i*16, float4-col t&15
    const int arow = t >> 4;            // 0..15
    const int acol = (t & 15) * 4;      // 0..60
    const float* agf = gru + (size_t)(m0 + arow) * H_D + acol;
    const int kc2 = (t & 15) >> 1;      // 16B k-chunk 0..7
    const int half = (t & 1) * 4;       // 8B half within chunk (in shorts)

    // B staging map (global_load_lds): row wave*8+(lane>>3)+i*32, XOR chunk
    const int srow = wave * 8 + (lane >> 3);
    const int koff = ((lane & 7) ^ (lane >> 3)) * 8;
    const ushort* bg = Wt + (size_t)(kb * 128 + srow) * H_D + koff;

    f32x4 acc[4][4];
    #pragma unroll
    for (int i = 0; i < 4; ++i)
        #pragma unroll
        for (int j = 0; j < 4; ++j)
            acc[i][j] = (f32x4){0.f, 0.f, 0.f, 0.f};

    for (int h0 = 0; h0 < H_D; h0 += 64) {
        // issue A fp32 loads before the barrier (regs only - safe)
        float4 av[8];
        #pragma unroll
        for (int i = 0; i < 8; ++i)
            av[i] = *(const float4*)(agf + h0 + (size_t)i * 16 * H_D);
        if (h0) __syncthreads();
        #pragma unroll
        for (int i = 0; i < 4; ++i)
            gl2lds16(bg + h0 + i * 32 * H_D, Bs + i * 2048 + wave * 512);
        // convert + stage A (XOR swizzle consistent with frag reads)
        #pragma unroll
        for (int i = 0; i < 8; ++i) {
            int row = i * 16 + arow;
            uint2 p = make_uint2(pkbf(av[i].x, av[i].y), pkbf(av[i].z, av[i].w));
            *(uint2*)(&As[row * 64 + ((kc2 ^ (row & 7)) << 3) + half]) = p;
        }
        __syncthreads();
        #pragma unroll
        for (int kk = 0; kk < 2; ++kk) {
            bf16x8 a[4], b[4];
            #pragma unroll
            for (int i = 0; i < 4; ++i) {
                int row = wm * 64 + i * 16 + ln;
                a[i] = *(const bf16x8*)(&As[row * 64 + (((kk << 2) + q) ^ x7) * 8]);
            }
            #pragma unroll
            for (int j = 0; j < 4; ++j) {
                int row = wn * 64 + j * 16 + ln;
                b[j] = *(const bf16x8*)(&Bs[row * 64 + (((kk << 2) + q) ^ x7) * 8]);
            }
            #pragma unroll
            for (int i = 0; i < 4; ++i)
                #pragma unroll
                for (int j = 0; j < 4; ++j)
                    acc[i][j] = __builtin_amdgcn_mfma_f32_16x16x32_bf16(a[i], b[j], acc[i][j], 0, 0, 0);
        }
    }

    // epilogue: e = tanh(C + cproj) * v ; reduce over this tile's 128 columns
    float cpv[4], vv[4];
    const float* cpn = cproj + nbatch * H_D;
    #pragma unroll
    for (int j = 0; j < 4; ++j) {
        int col = kb * 128 + wn * 64 + j * 16 + ln;
        cpv[j] = cpn[col];
        vv[j] = v[col];
    }
    #pragma unroll
    for (int i = 0; i < 4; ++i) {
        float s0 = 0.f, s1 = 0.f, s2 = 0.f, s3 = 0.f;
        #pragma unroll
        for (int j = 0; j < 4; ++j) {
            s0 += fast_tanh(acc[i][j][0] + cpv[j]) * vv[j];
            s1 += fast_tanh(acc[i][j][1] + cpv[j]) * vv[j];
            s2 += fast_tanh(acc[i][j][2] + cpv[j]) * vv[j];
            s3 += fast_tanh(acc[i][j][3] + cpv[j]) * vv[j];
        }
        #pragma unroll
        for (int off = 1; off < 16; off <<= 1) {
            s0 += __shfl_xor(s0, off);
            s1 += __shfl_xor(s1, off);
            s2 += __shfl_xor(s2, off);
            s3 += __shfl_xor(s3, off);
        }
        if (ln == 0) {
            red[wm][wn][i][q * 4 + 0] = s0;
            red[wm][wn][i][q * 4 + 1] = s1;
            red[wm][wn][i][q * 4 + 2] = s2;
            red[wm][wn][i][q * 4 + 3] = s3;
        }
    }
    __syncthreads();
    if (t < 128) {
        int wm2 = t >> 6, idx = t & 63;
        int i2 = idx >> 4, qr = idx & 15;
        float val = red[wm2][0][i2][qr] + red[wm2][1][i2][qr];
        spart[(size_t)kb * NT + m0 + wm2 * 64 + idx] = val;
    }
}

// ---------------- softmax over T per n, summing 8 kb-partials; 1024 threads
__global__ __launch_bounds__(1024) void softmax8_kernel(
    const float* __restrict__ spart, float* __restrict__ weights)
{
    const int n = blockIdx.x;
    const int t = threadIdx.x;   // 0..1023
    __shared__ float red[1024];
    float s0 = 0.f, s1 = 0.f;
    #pragma unroll
    for (int kb = 0; kb < 8; ++kb) {
        s0 += spart[(size_t)kb * NT + n * T_S + t];
        s1 += spart[(size_t)kb * NT + n * T_S + 1024 + t];
    }
    red[t] = fmaxf(s0, s1); __syncthreads();
    for (int s = 512; s > 0; s >>= 1) {
        if (t < s) red[t] = fmaxf(red[t], red[t + s]);
        __syncthreads();
    }
    const float mx = red[0];
    __syncthreads();
    float e0 = __expf(s0 - mx), e1 = __expf(s1 - mx);
    red[t] = e0 + e1; __syncthreads();
    for (int s = 512; s > 0; s >>= 1) {
        if (t < s) red[t] += red[t + s];
        __syncthreads();
    }
    const float inv = 1.0f / red[0];
    weights[n * T_S + t] = e0 * inv;
    weights[n * T_S + 1024 + t] = e1 * inv;
}

// ---------------- context partials from fp32 gru: cpart[tb][n][h]
// tb = 32 slices of 64 t; 1024 blocks; no atomics.
__global__ __launch_bounds__(256) void context4_kernel(
    const float* __restrict__ gru, const float* __restrict__ weights,
    float* __restrict__ cpart)
{
    const int tb = blockIdx.x;   // 0..31, 64 t each
    const int n  = blockIdx.y;   // 0..31
    const int t  = threadIdx.x;  // h-chunk: 4 h (16 B)
    float a0 = 0.f, a1 = 0.f, a2 = 0.f, a3 = 0.f;
    const float* wp = weights + n * T_S + tb * 64;
    const float* gp = gru + (size_t)(n * T_S + tb * 64) * H_D + t * 4;
    #pragma unroll 8
    for (int tt = 0; tt < 64; ++tt) {
        float w = wp[tt];
        float4 gv = *(const float4*)(gp + (size_t)tt * H_D);
        a0 = fmaf(w, gv.x, a0);
        a1 = fmaf(w, gv.y, a1);
        a2 = fmaf(w, gv.z, a2);
        a3 = fmaf(w, gv.w, a3);
    }
    *(float4*)(cpart + ((size_t)tb * N_B + n) * H_D + t * 4) =
        make_float4(a0, a1, a2, a3);
}

// ---------------- out[n][h] = sum_tb cpart[tb][n][h]
__global__ __launch_bounds__(256) void reduce_kernel(
    const float* __restrict__ cpart, float* __restrict__ out)
{
    const int idx = blockIdx.x * 256 + threadIdx.x;  // 32768
    float s = 0.f;
    #pragma unroll
    for (int tb = 0; tb < 32; ++tb)
        s += cpart[(size_t)tb * (N_B * H_D) + idx];
    out[idx] = s;
}

extern "C" void kernel_launch(void* const* d_in, const int* in_sizes, int n_in,
                              void* d_out, int out_size, void* d_ws, size_t ws_size,
                              hipStream_t stream)
{
    const float* gru  = (const float*)d_in[0];
    const float* cond = (const float*)d_in[1];
    const float* W_h  = (const float*)d_in[2];
    const float* W_c  = (const float*)d_in[3];
    const float* bias = (const float*)d_in[4];
    const float* v    = (const float*)d_in[5];
    float* out = (float*)d_out;

    char* ws = (char*)d_ws;
    const size_t szWt    = (size_t)H_D * H_D * 2;       // 2 MiB
    const size_t szCproj = (size_t)N_B * H_D * 4;       // 128 KiB
    const size_t szSpart = (size_t)8 * NT * 4;          // 2 MiB
    const size_t szWts   = (size_t)NT * 4;              // 256 KiB

    ushort* Wt    = (ushort*)ws;
    float* cproj  = (float*)(ws + szWt);
    float* spart  = (float*)(ws + szWt + szCproj);
    float* wts    = (float*)(ws + szWt + szCproj + szSpart);
    float* cpart  = (float*)(ws + szWt + szCproj + szSpart + szWts); // 4 MiB

    hipMemsetAsync(cproj, 0, szCproj, stream);
    transpose_kernel<<<256, 256, 0, stream>>>(W_h, Wt);
    cproj_kernel<<<dim3(128, 4), 256, 0, stream>>>(cond, W_c, bias, cproj);
    gemm4_kernel<<<4096, 256, 0, stream>>>(gru, Wt, cproj, v, spart);
    softmax8_kernel<<<N_B, 1024, 0, stream>>>(spart, wts);
    context4_kernel<<<dim3(32, N_B), 256, 0, stream>>>(gru, wts, cpart);
    reduce_kernel<<<128, 256, 0, stream>>>(cpart, out);
}